// Round 1
// 629.090 us; speedup vs baseline: 1.0342x; 1.0342x over previous
//
#include <hip/hip_runtime.h>
#include <math.h>

#define NB 2048
#define NC 64
#define NF 17
#define NCOL (NC * NF)   // 1088

// znorm pipeline geometry
#define ZPB 16                 // rows per partial block
#define ZNB (NB / ZPB)         // 128 partial blocks
// workspace layout:
//   [0,1024)            win  (float[256])
//   [1024,3072)         tw   (float2[256])
//   [4096,12800)        stats float2[NCOL]  (mu, sd+1e-6)
//   [16384, 16384+ZNB*NCOL*8)  partials float2[ZNB][NCOL]  (sum, sumsq)
#define WS_STATS_OFF 4096
#define WS_PART_OFF 16384
#define WS_FAST_BYTES (WS_PART_OFF + ZNB * NCOL * 8)   // 1,130,496

// Position of channel c in sorted(f'ch{i}_') order.
__device__ __constant__ int POS[64] = {
   0, 11, 22, 33, 44, 55, 60, 61, 62, 63,   // c = 0..9
   1,  2,  3,  4,  5,  6,  7,  8,  9, 10,   // c = 10..19
  12, 13, 14, 15, 16, 17, 18, 19, 20, 21,   // c = 20..29
  23, 24, 25, 26, 27, 28, 29, 30, 31, 32,   // c = 30..39
  34, 35, 36, 37, 38, 39, 40, 41, 42, 43,   // c = 40..49
  45, 46, 47, 48, 49, 50, 51, 52, 53, 54,   // c = 50..59
  56, 57, 58, 59                             // c = 60..63
};

// Feature index map (sorted names):
// 0 alpha_power 1 alpha_relative 2 beta_power 3 beta_relative 4 delta_power
// 5 delta_relative 6 entropy 7 gamma_power 8 gamma_relative 9 kurtosis
// 10 mean 11 peak_freq 12 rms 13 skew 14 std 15 theta_power 16 theta_relative

__global__ void init_tables(float* __restrict__ win, float2* __restrict__ tw) {
    int t = threadIdx.x;  // 256 threads
    double ang = (2.0 * 3.14159265358979323846 / 256.0) * (double)t;
    double cv = cos(ang), sv = sin(ang);
    win[t] = (float)(0.5 - 0.5 * cv);
    tw[t] = make_float2((float)cv, (float)sv);
}

// One wave (64 lanes) processes one (b,c) channel end-to-end.
// Block = 4 waves = 4 channels; the only __syncthreads is the table staging.
template <bool HAS_TAB>
__global__ __launch_bounds__(256) void feat_kernel(
    const float* __restrict__ x,
    const float* __restrict__ gwin, const float2* __restrict__ gtw,
    float* __restrict__ out)
{
    __shared__ __align__(16) float winS[256];
    __shared__ float2 twS[256];      // (cos, sin) of 2*pi*m/256
    __shared__ float2 tw16S[16];     // (cos, sin) of 2*pi*m/16
    // per-wave scratch: vseg[256] floats + T[16][18] float2 (= 576 floats)
    __shared__ __align__(16) float wmem[4 * 832];
    __shared__ unsigned histS[4][10];

    const int t = threadIdx.x;
    const int wid = t >> 6, l = t & 63;
    const int bc = (blockIdx.x << 2) + wid;
    const int b = bc >> 6, c = bc & 63;

    if (HAS_TAB) {
        winS[t] = gwin[t];
        twS[t] = gtw[t];
        if (t < 16) tw16S[t] = gtw[t << 4];
    } else {
        float ang = (float)t * (6.28318530717958647692f / 256.0f);
        float sv, cv;
        sincosf(ang, &sv, &cv);
        winS[t] = 0.5f - 0.5f * cv;
        twS[t] = make_float2(cv, sv);
        if (t < 16) {
            float a2 = (float)t * (6.28318530717958647692f / 16.0f);
            float s2v, c2v; sincosf(a2, &s2v, &c2v);
            tw16S[t] = make_float2(c2v, s2v);
        }
    }
    __syncthreads();

    float* vseg = &wmem[wid * 832];
    float2* T = reinterpret_cast<float2*>(&wmem[wid * 832 + 256]);
    unsigned* hist = histS[wid];

    // ---- load: lane holds x[8l .. 8l+7] ----
    const float4* xp4 = reinterpret_cast<const float4*>(x + (size_t)bc * 512);
    const float4 xa = xp4[2 * l], xb = xp4[2 * l + 1];
    float xe[8] = {xa.x, xa.y, xa.z, xa.w, xb.x, xb.y, xb.z, xb.w};

    // ---- pass 1: sums, min, max (+ 16-lane group sums for segment means) ----
    float psum = 0.f, s2 = 0.f, mn = xe[0], mx = xe[0];
#pragma unroll
    for (int e = 0; e < 8; e++) {
        psum += xe[e];
        s2 = fmaf(xe[e], xe[e], s2);
        mn = fminf(mn, xe[e]);
        mx = fmaxf(mx, xe[e]);
    }
    float g = psum;
#pragma unroll
    for (int m = 1; m < 16; m <<= 1) g += __shfl_xor(g, m, 64);
    const float g0 = __shfl(g, 0, 64), g1 = __shfl(g, 16, 64),
                g2 = __shfl(g, 32, 64), g3 = __shfl(g, 48, 64);
    const float S1 = (g0 + g1) + (g2 + g3);
#pragma unroll
    for (int m = 1; m < 64; m <<= 1) {
        s2 += __shfl_xor(s2, m, 64);
        mn = fminf(mn, __shfl_xor(mn, m, 64));
        mx = fmaxf(mx, __shfl_xor(mx, m, 64));
    }
    const float mean = S1 * (1.0f / 512.0f);

    // ---- pass 2: centered moments ----
    float c2 = 0.f, c3 = 0.f, c4 = 0.f;
#pragma unroll
    for (int e = 0; e < 8; e++) {
        float a = xe[e] - mean;
        float a2 = a * a;
        c2 += a2;
        c3 = fmaf(a2, a, c3);
        c4 = fmaf(a2, a2, c4);
    }
#pragma unroll
    for (int m = 1; m < 64; m <<= 1) {
        c2 += __shfl_xor(c2, m, 64);
        c3 += __shfl_xor(c3, m, 64);
        c4 += __shfl_xor(c4, m, 64);
    }
    const float m2 = c2 * (1.0f / 512.0f);
    const float m3 = c3 * (1.0f / 512.0f);
    const float m4 = c4 * (1.0f / 512.0f);
    const float stdv = sqrtf(m2);
    const float skew = m3 / (m2 * stdv);
    const float kurt = m4 / (m2 * m2) - 3.0f;
    const float rms = sqrtf(s2 * (1.0f / 512.0f));

    // ---- histogram (bit-exact fp32: sub, IEEE div, mul, trunc) ----
    if (l < 10) hist[l] = 0u;
    {
        float wdt = mx - mn;
        float safew = (wdt > 0.0f) ? wdt : 1.0f;
#pragma unroll
        for (int e = 0; e < 8; e++) {
            int bi = (int)((xe[e] - mn) / safew * 10.0f);
            bi = bi < 0 ? 0 : (bi > 9 ? 9 : bi);
            atomicAdd(&hist[bi], 1u);
        }
    }
    float entterm;
    {
        float cnt = (l < 10) ? (float)hist[l] : 0.0f;
        float p = cnt * (1.0f / 512.0f);
        entterm = (p > 0.0f) ? p * logf(p) : 0.0f;
#pragma unroll
        for (int m = 1; m < 16; m <<= 1) entterm += __shfl_xor(entterm, m, 64);
    }
    const float ent = -entterm;   // valid on lanes 0..15 (lane 6 uses it)

    // ---- hoisted twiddles (all from fp64-exact tables; W^m = (c, -s)) ----
    const int rb = l >> 4, n0 = l & 15;
    float2 tv;
    tv = tw16S[rb];             const float2 w16q1 = make_float2(tv.x, -tv.y);
    tv = tw16S[(2 * rb) & 15];  const float2 w16q2 = make_float2(tv.x, -tv.y);
    tv = tw16S[(3 * rb) & 15];  const float2 w16q3 = make_float2(tv.x, -tv.y);
    tv = twS[(4 * l) & 255];    const float2 step4 = make_float2(tv.x, -tv.y);
    tv = twS[l];                const float2 wq1 = make_float2(tv.x, -tv.y);
    tv = twS[(2 * l) & 255];    const float2 wq2 = make_float2(tv.x, -tv.y);
    tv = twS[(3 * l) & 255];    const float2 wq3 = make_float2(tv.x, -tv.y);
    // (-i)^((rb*a)&3) coefficients, a=0..3 (runtime rb -> +-1/0 floats)
    float car[4], cai[4];
#pragma unroll
    for (int a = 0; a < 4; a++) {
        int mm = (rb * a) & 3;
        car[a] = (mm == 0) ? 1.f : ((mm == 2) ? -1.f : 0.f);
        cai[a] = (mm == 1) ? -1.f : ((mm == 3) ? 1.f : 0.f);
    }

    // ---- Welch PSD: 3 segments, 256-pt DFT = (4x4) x (4x4) radix ----
    float P1 = 0.f, P2 = 0.f, P128 = 0.f;
#pragma unroll
    for (int s = 0; s < 3; s++) {
        const float smean =
            ((s == 0) ? (g0 + g1) : (s == 1) ? (g1 + g2) : (g2 + g3)) * (1.0f / 256.0f);
        const int D = l - 16 * s;   // active lanes hold 8 consecutive samples
        float alt = 0.f;
        if (D >= 0 && D < 32) {
            const float4 wA = reinterpret_cast<const float4*>(winS)[2 * D];
            const float4 wB = reinterpret_cast<const float4*>(winS)[2 * D + 1];
            float wv0 = wA.x * (xe[0] - smean);
            float wv1 = wA.y * (xe[1] - smean);
            float wv2 = wA.z * (xe[2] - smean);
            float wv3 = wA.w * (xe[3] - smean);
            float wv4 = wB.x * (xe[4] - smean);
            float wv5 = wB.y * (xe[5] - smean);
            float wv6 = wB.z * (xe[6] - smean);
            float wv7 = wB.w * (xe[7] - smean);
            reinterpret_cast<float4*>(vseg)[2 * D] = make_float4(wv0, wv1, wv2, wv3);
            reinterpret_cast<float4*>(vseg)[2 * D + 1] = make_float4(wv4, wv5, wv6, wv7);
            alt = ((wv0 - wv1) + (wv2 - wv3)) + ((wv4 - wv5) + (wv6 - wv7));
        }
        // X_128 = sum (-1)^n v_n  (real)
#pragma unroll
        for (int m = 1; m < 64; m <<= 1) alt += __shfl_xor(alt, m, 64);
        P128 = fmaf(alt, alt, P128);

        // stage 1: T[r][n0] = sum_n1 v[16 n1 + n0] W16^(r n1), r = rb + 4j
        float v[16];
#pragma unroll
        for (int n1 = 0; n1 < 16; n1++) v[n1] = vseg[16 * n1 + n0];
        float Dre[4], Dim[4];
#pragma unroll
        for (int q = 0; q < 4; q++) {
            float dr = v[q], di = 0.f;   // a=0 coeff = 1
#pragma unroll
            for (int a = 1; a < 4; a++) {
                float vv = v[4 * a + q];
                dr = fmaf(vv, car[a], dr);
                di = fmaf(vv, cai[a], di);
            }
            Dre[q] = dr; Dim[q] = di;
        }
        const float E0r = Dre[0], E0i = Dim[0];
        const float E1r = Dre[1] * w16q1.x - Dim[1] * w16q1.y;
        const float E1i = Dre[1] * w16q1.y + Dim[1] * w16q1.x;
        const float E2r = Dre[2] * w16q2.x - Dim[2] * w16q2.y;
        const float E2i = Dre[2] * w16q2.y + Dim[2] * w16q2.x;
        const float E3r = Dre[3] * w16q3.x - Dim[3] * w16q3.y;
        const float E3i = Dre[3] * w16q3.y + Dim[3] * w16q3.x;
        // T[rb+4j] = sum_q E_q * (-i)^(j q)   (compile-time sign/swap)
        T[(rb +  0) * 18 + n0] = make_float2((E0r + E1r) + (E2r + E3r),
                                             (E0i + E1i) + (E2i + E3i));
        T[(rb +  4) * 18 + n0] = make_float2((E0r + E1i) - (E2r + E3i),
                                             (E0i - E1r) + (E3r - E2i));
        T[(rb +  8) * 18 + n0] = make_float2((E0r - E1r) + (E2r - E3r),
                                             (E0i - E1i) + (E2i - E3i));
        T[(rb + 12) * 18 + n0] = make_float2((E0r - E1i) - (E2r - E3i),
                                             (E0i + E1r) - (E2i + E3r));

        // stage 2: k1 = l, k2 = l + 64 share row rr = l & 15
        float2 cur = make_float2(1.f, 0.f);
        float G0r = 0, G0i = 0, G1r = 0, G1i = 0, G2r = 0, G2i = 0, G3r = 0, G3i = 0;
#pragma unroll
        for (int a = 0; a < 4; a++) {
            const float4 t01 = *reinterpret_cast<const float4*>(&T[n0 * 18 + 4 * a]);
            const float4 t23 = *reinterpret_cast<const float4*>(&T[n0 * 18 + 4 * a + 2]);
            G0r = fmaf(t01.x, cur.x, fmaf(-t01.y, cur.y, G0r));
            G0i = fmaf(t01.x, cur.y, fmaf( t01.y, cur.x, G0i));
            G1r = fmaf(t01.z, cur.x, fmaf(-t01.w, cur.y, G1r));
            G1i = fmaf(t01.z, cur.y, fmaf( t01.w, cur.x, G1i));
            G2r = fmaf(t23.x, cur.x, fmaf(-t23.y, cur.y, G2r));
            G2i = fmaf(t23.x, cur.y, fmaf( t23.y, cur.x, G2i));
            G3r = fmaf(t23.z, cur.x, fmaf(-t23.w, cur.y, G3r));
            G3i = fmaf(t23.z, cur.y, fmaf( t23.w, cur.x, G3i));
            if (a < 3) {
                float nx = cur.x * step4.x - cur.y * step4.y;
                float ny = cur.x * step4.y + cur.y * step4.x;
                cur = make_float2(nx, ny);
            }
        }
        const float H0r = G0r, H0i = G0i;
        const float H1r = G1r * wq1.x - G1i * wq1.y, H1i = G1r * wq1.y + G1i * wq1.x;
        const float H2r = G2r * wq2.x - G2i * wq2.y, H2i = G2r * wq2.y + G2i * wq2.x;
        const float H3r = G3r * wq3.x - G3i * wq3.y, H3i = G3r * wq3.y + G3i * wq3.x;
        const float X1r = (H0r + H1r) + (H2r + H3r);
        const float X1i = (H0i + H1i) + (H2i + H3i);
        const float X2r = (H0r + H1i) - (H2r + H3i);   // sum H_q (-i)^q
        const float X2i = (H0i - H1r) + (H3r - H2i);
        P1 = fmaf(X1r, X1r, fmaf(X1i, X1i, P1));
        P2 = fmaf(X2r, X2r, fmaf(X2i, X2i, P2));
    }

    const float scc = (1.0f / 12288.0f) * (1.0f / 3.0f);
    const float psd1 = P1 * ((l == 0) ? 1.0f : 2.0f) * scc;   // k = l
    const float psd2 = P2 * 2.0f * scc;                        // k = l + 64
    const float psd128 = P128 * scc;                           // k = 128

    // ---- bands (trapz, dx = 0.5) + argmax ----
    auto wt = [](int k, int lo, int hi) -> float {
        if (k < lo || k > hi) return 0.0f;
        return (k == lo || k == hi) ? 0.25f : 0.5f;
    };
    float tot, al, be, de, ga, th, bv; int bi_;
    {
        const int k = l; const float p = psd1;
        tot = wt(k, 0, 128) * p;
        al = wt(k, 16, 24) * p; be = wt(k, 24, 60) * p; de = wt(k, 1, 8) * p;
        ga = wt(k, 60, 90) * p; th = wt(k, 8, 16) * p;
        bv = p; bi_ = k;
    }
    {
        const int k = l + 64; const float p = psd2;   // 64..127: interior of total
        tot += 0.5f * p;
        ga += wt(k, 60, 90) * p;
        if (p > bv) { bv = p; bi_ = k; }
    }
    if (l == 0) {
        tot += 0.25f * psd128;
        if (psd128 > bv) { bv = psd128; bi_ = 128; }
    }
#pragma unroll
    for (int m = 1; m < 64; m <<= 1) {
        tot += __shfl_xor(tot, m, 64);
        al  += __shfl_xor(al, m, 64);
        be  += __shfl_xor(be, m, 64);
        de  += __shfl_xor(de, m, 64);
        ga  += __shfl_xor(ga, m, 64);
        th  += __shfl_xor(th, m, 64);
        float ov = __shfl_xor(bv, m, 64);
        int   oi = __shfl_xor(bi_, m, 64);
        if (ov > bv || (ov == bv && oi < bi_)) { bv = ov; bi_ = oi; }
    }
    const bool ok = tot > 1e-6f;
    const float alR = ok ? al / tot : 0.f;
    const float beR = ok ? be / tot : 0.f;
    const float deR = ok ? de / tot : 0.f;
    const float gaR = ok ? ga / tot : 0.f;
    const float thR = ok ? th / tot : 0.f;
    const float pkf = 0.5f * (float)bi_;

    if (l < NF) {
        float fv =
            (l == 0)  ? al :
            (l == 1)  ? alR :
            (l == 2)  ? be :
            (l == 3)  ? beR :
            (l == 4)  ? de :
            (l == 5)  ? deR :
            (l == 6)  ? ent :
            (l == 7)  ? ga :
            (l == 8)  ? gaR :
            (l == 9)  ? kurt :
            (l == 10) ? mean :
            (l == 11) ? pkf :
            (l == 12) ? rms :
            (l == 13) ? skew :
            (l == 14) ? stdv :
            (l == 15) ? th : thR;
        out[(size_t)b * NCOL + POS[c] * NF + l] = fv;
    }
}

// ---------------- fast znorm pipeline (coalesced, 3 kernels) ----------------

// Z1: each block reduces ZPB=16 rows; threads sweep columns -> coalesced.
__global__ __launch_bounds__(256) void zstat_partial(
    const float* __restrict__ fm, float2* __restrict__ part)
{
    const int blk = blockIdx.x;          // 0..ZNB-1
    const int row0 = blk * ZPB;
    for (int c = threadIdx.x; c < NCOL; c += 256) {
        float s = 0.f, ss = 0.f;
#pragma unroll
        for (int r = 0; r < ZPB; r++) {
            float v = fm[(size_t)(row0 + r) * NCOL + c];
            s += v;
            ss = fmaf(v, v, ss);
        }
        part[(size_t)blk * NCOL + c] = make_float2(s, ss);
    }
}

// Z2: reduce ZNB partials per column in fp64 (avoids E[x^2]-mu^2 cancellation
// for tight-variance columns like entropy/rms); store (mu, sd+1e-6).
__global__ __launch_bounds__(256) void zstat_final(
    const float2* __restrict__ part, float2* __restrict__ stats)
{
    const int c = blockIdx.x * 256 + threadIdx.x;
    if (c >= NCOL) return;
    double s = 0.0, ss = 0.0;
    for (int b = 0; b < ZNB; b++) {
        float2 p = part[(size_t)b * NCOL + c];
        s += (double)p.x;
        ss += (double)p.y;
    }
    const double mu_d = s * (1.0 / 2048.0);
    double var_d = ss * (1.0 / 2048.0) - mu_d * mu_d;
    if (var_d < 0.0) var_d = 0.0;
    const float mu = (float)mu_d;
    const float sd = sqrtf((float)var_d);
    stats[c] = make_float2(mu, sd + 1e-6f);
}

// Z3: coalesced apply, identical op to the old kernel: (v - mu) / den.
__global__ __launch_bounds__(256) void zapply(
    float* __restrict__ fm, const float2* __restrict__ stats)
{
    const int row = blockIdx.x;          // 0..NB-1
    float4* p4 = reinterpret_cast<float4*>(fm + (size_t)row * NCOL);
    for (int i = threadIdx.x; i < NCOL / 4; i += 256) {
        float4 v = p4[i];
        const float2 s0 = stats[4 * i + 0];
        const float2 s1 = stats[4 * i + 1];
        const float2 s2 = stats[4 * i + 2];
        const float2 s3 = stats[4 * i + 3];
        v.x = (v.x - s0.x) / s0.y;
        v.y = (v.y - s1.x) / s1.y;
        v.z = (v.z - s2.x) / s2.y;
        v.w = (v.w - s3.x) / s3.y;
        p4[i] = v;
    }
}

// ---------------- fallback znorm (old, column-per-block) ----------------
__global__ __launch_bounds__(256) void znorm_kernel(float* __restrict__ fm) {
    __shared__ float red[4];
    const int col = blockIdx.x;    // 1088 columns
    const int t = threadIdx.x;
    const int wid = t >> 6, lane = t & 63;
    float v[8];
    float s = 0.0f;
#pragma unroll
    for (int i = 0; i < 8; i++) {
        v[i] = fm[(size_t)(i * 256 + t) * NCOL + col];
        s += v[i];
    }
#pragma unroll
    for (int off = 32; off; off >>= 1) s += __shfl_down(s, off, 64);
    if (lane == 0) red[wid] = s;
    __syncthreads();
    const float mu = (red[0] + red[1] + red[2] + red[3]) * (1.0f / 2048.0f);
    __syncthreads();
    float q = 0.0f;
#pragma unroll
    for (int i = 0; i < 8; i++) {
        float dd = v[i] - mu;
        q += dd * dd;
    }
#pragma unroll
    for (int off = 32; off; off >>= 1) q += __shfl_down(q, off, 64);
    if (lane == 0) red[wid] = q;
    __syncthreads();
    const float sd = sqrtf((red[0] + red[1] + red[2] + red[3]) * (1.0f / 2048.0f));
    const float den = sd + 1e-6f;
#pragma unroll
    for (int i = 0; i < 8; i++)
        fm[(size_t)(i * 256 + t) * NCOL + col] = (v[i] - mu) / den;
}

extern "C" void kernel_launch(void* const* d_in, const int* in_sizes, int n_in,
                              void* d_out, int out_size, void* d_ws, size_t ws_size,
                              hipStream_t stream) {
    const float* x = (const float*)d_in[0];
    float* out = (float*)d_out;
    const int nblocks = (NB * NC) / 4;   // one wave per channel, 4 waves/block

    const bool has_tab = (d_ws != nullptr && ws_size >= 4096);
    const bool fast_z = (d_ws != nullptr && ws_size >= (size_t)WS_FAST_BYTES);

    if (has_tab) {
        float* win = (float*)d_ws;
        float2* tw = (float2*)((char*)d_ws + 1024);
        init_tables<<<1, 256, 0, stream>>>(win, tw);
        feat_kernel<true><<<nblocks, 256, 0, stream>>>(x, win, tw, out);
    } else {
        feat_kernel<false><<<nblocks, 256, 0, stream>>>(x, nullptr, nullptr, out);
    }

    if (fast_z) {
        float2* stats = (float2*)((char*)d_ws + WS_STATS_OFF);
        float2* part = (float2*)((char*)d_ws + WS_PART_OFF);
        zstat_partial<<<ZNB, 256, 0, stream>>>(out, part);
        zstat_final<<<(NCOL + 255) / 256, 256, 0, stream>>>(part, stats);
        zapply<<<NB, 256, 0, stream>>>(out, stats);
    } else {
        znorm_kernel<<<NCOL, 256, 0, stream>>>(out);
    }
}

// Round 4
// 614.233 us; speedup vs baseline: 1.0592x; 1.0242x over previous
//
#include <hip/hip_runtime.h>
#include <math.h>

#define NB 2048
#define NC 64
#define NF 17
#define NCOL (NC * NF)   // 1088

// znorm pipeline geometry
#define ZPB 16                 // rows per partial block
#define ZNB (NB / ZPB)         // 128 partial blocks
#define WS_STATS_OFF 4096
#define WS_PART_OFF 16384
#define WS_FAST_BYTES (WS_PART_OFF + ZNB * NCOL * 8)   // 1,130,496

// Position of channel c in sorted(f'ch{i}_') order.
__device__ __constant__ int POS[64] = {
   0, 11, 22, 33, 44, 55, 60, 61, 62, 63,   // c = 0..9
   1,  2,  3,  4,  5,  6,  7,  8,  9, 10,   // c = 10..19
  12, 13, 14, 15, 16, 17, 18, 19, 20, 21,   // c = 20..29
  23, 24, 25, 26, 27, 28, 29, 30, 31, 32,   // c = 30..39
  34, 35, 36, 37, 38, 39, 40, 41, 42, 43,   // c = 40..49
  45, 46, 47, 48, 49, 50, 51, 52, 53, 54,   // c = 50..59
  56, 57, 58, 59                             // c = 60..63
};

__global__ void init_tables(float* __restrict__ win, float2* __restrict__ tw) {
    int t = threadIdx.x;  // 256 threads
    double ang = (2.0 * 3.14159265358979323846 / 256.0) * (double)t;
    double cv = cos(ang), sv = sin(ang);
    win[t] = (float)(0.5 - 0.5 * cv);
    tw[t] = make_float2((float)cv, (float)sv);
}

// One wave (64 lanes) processes one (b,c) channel end-to-end.
// NOTE: default launch bounds — the forced (256,8) build coincided with two
// container failures; reverted to the known-good config while keeping the
// register-slimming changes (natural VGPR drop expected).
template <bool HAS_TAB>
__global__ __launch_bounds__(256) void feat_kernel(
    const float* __restrict__ x,
    const float* __restrict__ gwin, const float2* __restrict__ gtw,
    float* __restrict__ out)
{
    __shared__ __align__(16) float winS[256];
    __shared__ float2 twS[256];      // (cos, sin) of 2*pi*m/256
    __shared__ float2 tw16S[16];     // (cos, sin) of 2*pi*m/16
    // per-wave scratch: vseg[256] floats + T[16][18] float2 (= 576 floats)
    __shared__ __align__(16) float wmem[4 * 832];
    // 4 copies per wave to cut same-address atomic serialization 4x.
    // layout: hist[bin*4 + (lane&3)]
    __shared__ unsigned histS[4][40];

    const int t = threadIdx.x;
    const int wid = t >> 6, l = t & 63;
    const int bc = (blockIdx.x << 2) + wid;

    if (HAS_TAB) {
        winS[t] = gwin[t];
        twS[t] = gtw[t];
        if (t < 16) tw16S[t] = gtw[t << 4];
    } else {
        float ang = (float)t * (6.28318530717958647692f / 256.0f);
        float sv, cv;
        sincosf(ang, &sv, &cv);
        winS[t] = 0.5f - 0.5f * cv;
        twS[t] = make_float2(cv, sv);
        if (t < 16) {
            float a2 = (float)t * (6.28318530717958647692f / 16.0f);
            float s2v, c2v; sincosf(a2, &s2v, &c2v);
            tw16S[t] = make_float2(c2v, s2v);
        }
    }
    __syncthreads();

    float* vseg = &wmem[wid * 832];
    float2* T = reinterpret_cast<float2*>(&wmem[wid * 832 + 256]);
    unsigned* hist = histS[wid];

    // ---- load: lane holds x[8l .. 8l+7] ----
    const float4* xp4 = reinterpret_cast<const float4*>(x + (size_t)bc * 512);
    const float4 xa = xp4[2 * l], xb = xp4[2 * l + 1];
    float xe[8] = {xa.x, xa.y, xa.z, xa.w, xb.x, xb.y, xb.z, xb.w};

    // ---- pass 1: sums, min, max (+ 16-lane group sums for segment means) ----
    float psum = 0.f, s2 = 0.f, mn = xe[0], mx = xe[0];
#pragma unroll
    for (int e = 0; e < 8; e++) {
        psum += xe[e];
        s2 = fmaf(xe[e], xe[e], s2);
        mn = fminf(mn, xe[e]);
        mx = fmaxf(mx, xe[e]);
    }
    float g = psum;
#pragma unroll
    for (int m = 1; m < 16; m <<= 1) g += __shfl_xor(g, m, 64);
    const float g0 = __shfl(g, 0, 64), g1 = __shfl(g, 16, 64),
                g2 = __shfl(g, 32, 64), g3 = __shfl(g, 48, 64);
    const float S1 = (g0 + g1) + (g2 + g3);
#pragma unroll
    for (int m = 1; m < 64; m <<= 1) {
        s2 += __shfl_xor(s2, m, 64);
        mn = fminf(mn, __shfl_xor(mn, m, 64));
        mx = fmaxf(mx, __shfl_xor(mx, m, 64));
    }
    const float mean = S1 * (1.0f / 512.0f);

    // ---- pass 2: centered moments ----
    float c2 = 0.f, c3 = 0.f, c4 = 0.f;
#pragma unroll
    for (int e = 0; e < 8; e++) {
        float a = xe[e] - mean;
        float a2 = a * a;
        c2 += a2;
        c3 = fmaf(a2, a, c3);
        c4 = fmaf(a2, a2, c4);
    }
#pragma unroll
    for (int m = 1; m < 64; m <<= 1) {
        c2 += __shfl_xor(c2, m, 64);
        c3 += __shfl_xor(c3, m, 64);
        c4 += __shfl_xor(c4, m, 64);
    }
    const float m2 = c2 * (1.0f / 512.0f);
    const float m3 = c3 * (1.0f / 512.0f);
    const float m4 = c4 * (1.0f / 512.0f);
    const float stdv = sqrtf(m2);
    const float skew = m3 / (m2 * stdv);
    const float kurt = m4 / (m2 * m2) - 3.0f;
    const float rms = sqrtf(s2 * (1.0f / 512.0f));

    // ---- histogram (bit-exact fp32: sub, IEEE div, mul, trunc) ----
    if (l < 40) hist[l] = 0u;
    {
        float wdt = mx - mn;
        float safew = (wdt > 0.0f) ? wdt : 1.0f;
        const int cpy = l & 3;
#pragma unroll
        for (int e = 0; e < 8; e++) {
            int bi = (int)((xe[e] - mn) / safew * 10.0f);
            bi = bi < 0 ? 0 : (bi > 9 ? 9 : bi);
            atomicAdd(&hist[bi * 4 + cpy], 1u);
        }
    }
    float entterm;
    {
        float cnt = 0.0f;
        if (l < 10) {
            unsigned cc = hist[4 * l] + hist[4 * l + 1] + hist[4 * l + 2] + hist[4 * l + 3];
            cnt = (float)cc;
        }
        float p = cnt * (1.0f / 512.0f);
        entterm = (p > 0.0f) ? p * logf(p) : 0.0f;
#pragma unroll
        for (int m = 1; m < 16; m <<= 1) entterm += __shfl_xor(entterm, m, 64);
    }
    const float ent = -entterm;   // valid on lanes 0..15 (lane 6 uses it)

    // ---- hoisted twiddles (fp64-exact tables; W^m = (c, -s)) ----
    const int rb = l >> 4, n0 = l & 15;
    float2 tv;
    tv = tw16S[rb];             const float2 w16q1 = make_float2(tv.x, -tv.y);
    tv = tw16S[(2 * rb) & 15];  const float2 w16q2 = make_float2(tv.x, -tv.y);
    tv = tw16S[(3 * rb) & 15];  const float2 w16q3 = make_float2(tv.x, -tv.y);
    tv = twS[l];                const float2 wq1 = make_float2(tv.x, -tv.y);
    tv = twS[(2 * l) & 255];    const float2 wq2 = make_float2(tv.x, -tv.y);
    tv = twS[(3 * l) & 255];    const float2 wq3 = make_float2(tv.x, -tv.y);
    // (-i)^((rb*a)&3) coefficients, a=0..3 (runtime rb -> +-1/0 floats)
    float car[4], cai[4];
#pragma unroll
    for (int a = 0; a < 4; a++) {
        int mm = (rb * a) & 3;
        car[a] = (mm == 0) ? 1.f : ((mm == 2) ? -1.f : 0.f);
        cai[a] = (mm == 1) ? -1.f : ((mm == 3) ? 1.f : 0.f);
    }

    // ---- Welch PSD: 3 segments, 256-pt DFT = (4x4) x (4x4) radix ----
    float P1 = 0.f, P2 = 0.f, P128 = 0.f;
#pragma unroll
    for (int s = 0; s < 3; s++) {
        const float smean =
            ((s == 0) ? (g0 + g1) : (s == 1) ? (g1 + g2) : (g2 + g3)) * (1.0f / 256.0f);
        const int D = l - 16 * s;   // active lanes hold 8 consecutive samples
        float alt = 0.f;
        if (D >= 0 && D < 32) {
            const float4 wA = reinterpret_cast<const float4*>(winS)[2 * D];
            const float4 wB = reinterpret_cast<const float4*>(winS)[2 * D + 1];
            float wv0 = wA.x * (xe[0] - smean);
            float wv1 = wA.y * (xe[1] - smean);
            float wv2 = wA.z * (xe[2] - smean);
            float wv3 = wA.w * (xe[3] - smean);
            float wv4 = wB.x * (xe[4] - smean);
            float wv5 = wB.y * (xe[5] - smean);
            float wv6 = wB.z * (xe[6] - smean);
            float wv7 = wB.w * (xe[7] - smean);
            reinterpret_cast<float4*>(vseg)[2 * D] = make_float4(wv0, wv1, wv2, wv3);
            reinterpret_cast<float4*>(vseg)[2 * D + 1] = make_float4(wv4, wv5, wv6, wv7);
            alt = ((wv0 - wv1) + (wv2 - wv3)) + ((wv4 - wv5) + (wv6 - wv7));
        }
        // X_128 = sum (-1)^n v_n  (real)
#pragma unroll
        for (int m = 1; m < 64; m <<= 1) alt += __shfl_xor(alt, m, 64);
        P128 = fmaf(alt, alt, P128);

        // stage 1: T[r][n0] = sum_n1 v[16 n1 + n0] W16^(r n1), r = rb + 4j
        // v[n1] = vseg[16*n1 + n0] read in-place (4 live at a time, not 16).
        float Dre[4], Dim[4];
#pragma unroll
        for (int q = 0; q < 4; q++) {
            float dr = vseg[16 * q + n0], di = 0.f;   // a=0 coeff = 1
#pragma unroll
            for (int a = 1; a < 4; a++) {
                float vv = vseg[64 * a + 16 * q + n0];
                dr = fmaf(vv, car[a], dr);
                di = fmaf(vv, cai[a], di);
            }
            Dre[q] = dr; Dim[q] = di;
        }
        const float E0r = Dre[0], E0i = Dim[0];
        const float E1r = Dre[1] * w16q1.x - Dim[1] * w16q1.y;
        const float E1i = Dre[1] * w16q1.y + Dim[1] * w16q1.x;
        const float E2r = Dre[2] * w16q2.x - Dim[2] * w16q2.y;
        const float E2i = Dre[2] * w16q2.y + Dim[2] * w16q2.x;
        const float E3r = Dre[3] * w16q3.x - Dim[3] * w16q3.y;
        const float E3i = Dre[3] * w16q3.y + Dim[3] * w16q3.x;
        // T[rb+4j] = sum_q E_q * (-i)^(j q)   (compile-time sign/swap)
        T[(rb +  0) * 18 + n0] = make_float2((E0r + E1r) + (E2r + E3r),
                                             (E0i + E1i) + (E2i + E3i));
        T[(rb +  4) * 18 + n0] = make_float2((E0r + E1i) - (E2r + E3i),
                                             (E0i - E1r) + (E3r - E2i));
        T[(rb +  8) * 18 + n0] = make_float2((E0r - E1r) + (E2r - E3r),
                                             (E0i - E1i) + (E2i - E3i));
        T[(rb + 12) * 18 + n0] = make_float2((E0r - E1i) - (E2r - E3i),
                                             (E0i + E1r) - (E2i + E3r));

        // stage 2: k1 = l, k2 = l + 64 share row rr = l & 15
        // twiddle cur_a = W_256^{4 l a} read exactly from table (no recurrence)
        float G0r, G0i, G1r, G1i, G2r, G2i, G3r, G3i;
        {
            const float4 t01 = *reinterpret_cast<const float4*>(&T[n0 * 18 + 0]);
            const float4 t23 = *reinterpret_cast<const float4*>(&T[n0 * 18 + 2]);
            G0r = t01.x; G0i = t01.y; G1r = t01.z; G1i = t01.w;
            G2r = t23.x; G2i = t23.y; G3r = t23.z; G3i = t23.w;
        }
#pragma unroll
        for (int a = 1; a < 4; a++) {
            float2 cw = twS[(4 * l * a) & 255];
            const float cx = cw.x, cy = -cw.y;
            const float4 t01 = *reinterpret_cast<const float4*>(&T[n0 * 18 + 4 * a]);
            const float4 t23 = *reinterpret_cast<const float4*>(&T[n0 * 18 + 4 * a + 2]);
            G0r = fmaf(t01.x, cx, fmaf(-t01.y, cy, G0r));
            G0i = fmaf(t01.x, cy, fmaf( t01.y, cx, G0i));
            G1r = fmaf(t01.z, cx, fmaf(-t01.w, cy, G1r));
            G1i = fmaf(t01.z, cy, fmaf( t01.w, cx, G1i));
            G2r = fmaf(t23.x, cx, fmaf(-t23.y, cy, G2r));
            G2i = fmaf(t23.x, cy, fmaf( t23.y, cx, G2i));
            G3r = fmaf(t23.z, cx, fmaf(-t23.w, cy, G3r));
            G3i = fmaf(t23.z, cy, fmaf( t23.w, cx, G3i));
        }
        const float H0r = G0r, H0i = G0i;
        const float H1r = G1r * wq1.x - G1i * wq1.y, H1i = G1r * wq1.y + G1i * wq1.x;
        const float H2r = G2r * wq2.x - G2i * wq2.y, H2i = G2r * wq2.y + G2i * wq2.x;
        const float H3r = G3r * wq3.x - G3i * wq3.y, H3i = G3r * wq3.y + G3i * wq3.x;
        const float X1r = (H0r + H1r) + (H2r + H3r);
        const float X1i = (H0i + H1i) + (H2i + H3i);
        const float X2r = (H0r + H1i) - (H2r + H3i);   // sum H_q (-i)^q
        const float X2i = (H0i - H1r) + (H3r - H2i);
        P1 = fmaf(X1r, X1r, fmaf(X1i, X1i, P1));
        P2 = fmaf(X2r, X2r, fmaf(X2i, X2i, P2));
    }

    const float scc = (1.0f / 12288.0f) * (1.0f / 3.0f);
    const float psd1 = P1 * ((l == 0) ? 1.0f : 2.0f) * scc;   // k = l
    const float psd2 = P2 * 2.0f * scc;                        // k = l + 64
    const float psd128 = P128 * scc;                           // k = 128

    // ---- bands (trapz, dx = 0.5) + argmax ----
    auto wt = [](int k, int lo, int hi) -> float {
        if (k < lo || k > hi) return 0.0f;
        return (k == lo || k == hi) ? 0.25f : 0.5f;
    };
    float tot, al, be, de, ga, th, bv; int bi_;
    {
        const int k = l; const float p = psd1;
        tot = wt(k, 0, 128) * p;
        al = wt(k, 16, 24) * p; be = wt(k, 24, 60) * p; de = wt(k, 1, 8) * p;
        ga = wt(k, 60, 90) * p; th = wt(k, 8, 16) * p;
        bv = p; bi_ = k;
    }
    {
        const int k = l + 64; const float p = psd2;   // 64..127: interior of total
        tot += 0.5f * p;
        ga += wt(k, 60, 90) * p;
        if (p > bv) { bv = p; bi_ = k; }
    }
    if (l == 0) {
        tot += 0.25f * psd128;
        if (psd128 > bv) { bv = psd128; bi_ = 128; }
    }
    // packed (value, 16384-k) u64 max == same tie-break as (ov>bv)||(ov==bv&&oi<bi)
    unsigned long long pk =
        ((unsigned long long)__float_as_uint(bv) << 32) | (unsigned)(16384 - bi_);
#pragma unroll
    for (int m = 1; m < 64; m <<= 1) {
        tot += __shfl_xor(tot, m, 64);
        al  += __shfl_xor(al, m, 64);
        be  += __shfl_xor(be, m, 64);
        de  += __shfl_xor(de, m, 64);
        ga  += __shfl_xor(ga, m, 64);
        th  += __shfl_xor(th, m, 64);
        unsigned long long op = __shfl_xor(pk, m, 64);
        pk = (op > pk) ? op : pk;
    }
    bi_ = 16384 - (int)(unsigned)(pk & 0xffffffffull);
    const bool ok = tot > 1e-6f;
    const float alR = ok ? al / tot : 0.f;
    const float beR = ok ? be / tot : 0.f;
    const float deR = ok ? de / tot : 0.f;
    const float gaR = ok ? ga / tot : 0.f;
    const float thR = ok ? th / tot : 0.f;
    const float pkf = 0.5f * (float)bi_;

    if (l < NF) {
        const int b = bc >> 6, c = bc & 63;
        float fv =
            (l == 0)  ? al :
            (l == 1)  ? alR :
            (l == 2)  ? be :
            (l == 3)  ? beR :
            (l == 4)  ? de :
            (l == 5)  ? deR :
            (l == 6)  ? ent :
            (l == 7)  ? ga :
            (l == 8)  ? gaR :
            (l == 9)  ? kurt :
            (l == 10) ? mean :
            (l == 11) ? pkf :
            (l == 12) ? rms :
            (l == 13) ? skew :
            (l == 14) ? stdv :
            (l == 15) ? th : thR;
        out[(size_t)b * NCOL + POS[c] * NF + l] = fv;
    }
}

// ---------------- fast znorm pipeline (coalesced, 3 kernels) ----------------

__global__ __launch_bounds__(256) void zstat_partial(
    const float* __restrict__ fm, float2* __restrict__ part)
{
    const int blk = blockIdx.x;          // 0..ZNB-1
    const int row0 = blk * ZPB;
    for (int c = threadIdx.x; c < NCOL; c += 256) {
        float s = 0.f, ss = 0.f;
#pragma unroll
        for (int r = 0; r < ZPB; r++) {
            float v = fm[(size_t)(row0 + r) * NCOL + c];
            s += v;
            ss = fmaf(v, v, ss);
        }
        part[(size_t)blk * NCOL + c] = make_float2(s, ss);
    }
}

__global__ __launch_bounds__(256) void zstat_final(
    const float2* __restrict__ part, float2* __restrict__ stats)
{
    const int c = blockIdx.x * 256 + threadIdx.x;
    if (c >= NCOL) return;
    double s = 0.0, ss = 0.0;
    for (int b = 0; b < ZNB; b++) {
        float2 p = part[(size_t)b * NCOL + c];
        s += (double)p.x;
        ss += (double)p.y;
    }
    const double mu_d = s * (1.0 / 2048.0);
    double var_d = ss * (1.0 / 2048.0) - mu_d * mu_d;
    if (var_d < 0.0) var_d = 0.0;
    const float mu = (float)mu_d;
    const float sd = sqrtf((float)var_d);
    stats[c] = make_float2(mu, sd + 1e-6f);
}

__global__ __launch_bounds__(256) void zapply(
    float* __restrict__ fm, const float2* __restrict__ stats)
{
    const int row = blockIdx.x;          // 0..NB-1
    float4* p4 = reinterpret_cast<float4*>(fm + (size_t)row * NCOL);
    for (int i = threadIdx.x; i < NCOL / 4; i += 256) {
        float4 v = p4[i];
        const float2 s0 = stats[4 * i + 0];
        const float2 s1 = stats[4 * i + 1];
        const float2 s2 = stats[4 * i + 2];
        const float2 s3 = stats[4 * i + 3];
        v.x = (v.x - s0.x) / s0.y;
        v.y = (v.y - s1.x) / s1.y;
        v.z = (v.z - s2.x) / s2.y;
        v.w = (v.w - s3.x) / s3.y;
        p4[i] = v;
    }
}

// ---------------- fallback znorm (old, column-per-block) ----------------
__global__ __launch_bounds__(256) void znorm_kernel(float* __restrict__ fm) {
    __shared__ float red[4];
    const int col = blockIdx.x;    // 1088 columns
    const int t = threadIdx.x;
    const int wid = t >> 6, lane = t & 63;
    float v[8];
    float s = 0.0f;
#pragma unroll
    for (int i = 0; i < 8; i++) {
        v[i] = fm[(size_t)(i * 256 + t) * NCOL + col];
        s += v[i];
    }
#pragma unroll
    for (int off = 32; off; off >>= 1) s += __shfl_down(s, off, 64);
    if (lane == 0) red[wid] = s;
    __syncthreads();
    const float mu = (red[0] + red[1] + red[2] + red[3]) * (1.0f / 2048.0f);
    __syncthreads();
    float q = 0.0f;
#pragma unroll
    for (int i = 0; i < 8; i++) {
        float dd = v[i] - mu;
        q += dd * dd;
    }
#pragma unroll
    for (int off = 32; off; off >>= 1) q += __shfl_down(q, off, 64);
    if (lane == 0) red[wid] = q;
    __syncthreads();
    const float sd = sqrtf((red[0] + red[1] + red[2] + red[3]) * (1.0f / 2048.0f));
    const float den = sd + 1e-6f;
#pragma unroll
    for (int i = 0; i < 8; i++)
        fm[(size_t)(i * 256 + t) * NCOL + col] = (v[i] - mu) / den;
}

extern "C" void kernel_launch(void* const* d_in, const int* in_sizes, int n_in,
                              void* d_out, int out_size, void* d_ws, size_t ws_size,
                              hipStream_t stream) {
    const float* x = (const float*)d_in[0];
    float* out = (float*)d_out;
    const int nblocks = (NB * NC) / 4;   // one wave per channel, 4 waves/block

    const bool has_tab = (d_ws != nullptr && ws_size >= 4096);
    const bool fast_z = (d_ws != nullptr && ws_size >= (size_t)WS_FAST_BYTES);

    if (has_tab) {
        float* win = (float*)d_ws;
        float2* tw = (float2*)((char*)d_ws + 1024);
        init_tables<<<1, 256, 0, stream>>>(win, tw);
        feat_kernel<true><<<nblocks, 256, 0, stream>>>(x, win, tw, out);
    } else {
        feat_kernel<false><<<nblocks, 256, 0, stream>>>(x, nullptr, nullptr, out);
    }

    if (fast_z) {
        float2* stats = (float2*)((char*)d_ws + WS_STATS_OFF);
        float2* part = (float2*)((char*)d_ws + WS_PART_OFF);
        zstat_partial<<<ZNB, 256, 0, stream>>>(out, part);
        zstat_final<<<(NCOL + 255) / 256, 256, 0, stream>>>(part, stats);
        zapply<<<NB, 256, 0, stream>>>(out, stats);
    } else {
        znorm_kernel<<<NCOL, 256, 0, stream>>>(out);
    }
}